// Round 3
// baseline (68966.595 us; speedup 1.0000x reference)
//
#include <hip/hip_runtime.h>
#include <hip/hip_fp16.h>
#include <stdint.h>

// ---------------- problem constants ----------------
#define T_STEPS 1000
#define BATCH   128
#define HID     256
#define G4      1024
#define INSZ    2
#define NOUT    100
#define NW      20
#define NTHM    256     // threads per WG (4 waves, 1/SIMD)
#define NGROUPS 32      // batch groups of 4 rows
#define NSLICE  8       // WGs per group

// ---------------- ws layout (dword offsets) ----------------
// Sync/head/misc regions fit in <0.6 MB (always available); the packed
// register-image (2.62 MB) is optional — without it the main kernel gathers
// weights from the original tensors at startup.
constexpr int    OFF_HBUF  = 0;                          // [32][3][2][4][128] dw  h exchange
constexpr int    OFF_CNT   = OFF_HBUF + 32 * 3 * 2 * 4 * 128;   // 98304; [32][3][16]
constexpr int    OFF_HEADW = OFF_CNT + 32 * 48;          // 99840; [120][129] fp16-pair dw (padded stride)
constexpr int    OFF_HXB   = OFF_HEADW + 120 * 129;      // 115320; [120][3] fp32 (bias, wx0, wx1)
constexpr int    OFF_MISC  = OFF_HXB + 360;              // 115680; [8][12][256] fp32
constexpr int    OFF_WREG  = OFF_MISC + 8 * 12 * 256;    // 140256; [8][320][256] packed fp16 pairs
constexpr size_t WS_FULL_DW = (size_t)OFF_WREG + 8 * 320 * 256;  // 795,616 dw = 3.18 MB
constexpr size_t GOFF = (size_t)BATCH * T_STEPS * NOUT;  // output offset of softmax part

__device__ __forceinline__ float sigf(float x)     { return 1.0f / (1.0f + __expf(-x)); }
__device__ __forceinline__ float tanhfast(float x) { return 2.0f / (1.0f + __expf(-2.0f * x)) - 1.0f; }

typedef _Float16 h2v __attribute__((ext_vector_type(2)));
__device__ __forceinline__ float dot2f(uint32_t w, uint32_t h, float acc) {
    return __builtin_amdgcn_fdot2(__builtin_bit_cast(h2v, w),
                                  __builtin_bit_cast(h2v, h), acc, false);
}
__device__ __forceinline__ uint32_t pk(float a, float b) {
    __half2 h = __floats2half2_rn(a, b);
    return *reinterpret_cast<uint32_t*>(&h);
}

// Weight-slice element for (wg-slice w, lane, reg d). Shared by the pack
// kernel and the direct-gather path so layouts can never diverge.
// lane -> col c=lane>>1 (c = gate*32+ni -> j = gate*256 + w*32 + ni), half=lane&1.
// d: [0,64) L0 recur | [64,128) L1 skip | [128,192) L1 recur
//    [192,256) L2 skip | [256,320) L2 recur.  k = half*128 + 2*i.
__device__ __forceinline__ uint32_t fetch_wdw(int w, int lane, int d,
                                              const float* __restrict__ Whh0,
                                              const float* __restrict__ WihL,
                                              const float* __restrict__ WhhL) {
    int c = lane >> 1, half = lane & 1;
    int j = (c >> 5) * 256 + w * 32 + (c & 31);
    if (d < 64)  { int k = half * 128 + 2 * d;
        return pk(Whh0[(size_t)j * 256 + k], Whh0[(size_t)j * 256 + k + 1]); }
    if (d < 128) { int k = half * 128 + 2 * (d - 64);
        return pk(WihL[(size_t)j * 258 + 2 + k], WihL[(size_t)j * 258 + 3 + k]); }
    if (d < 192) { int k = half * 128 + 2 * (d - 128);
        return pk(WhhL[(size_t)j * 256 + k], WhhL[(size_t)j * 256 + k + 1]); }
    if (d < 256) { int k = half * 128 + 2 * (d - 192);
        const float* W = WihL + (size_t)G4 * 258;
        return pk(W[(size_t)j * 258 + 2 + k], W[(size_t)j * 258 + 3 + k]); }
    {            int k = half * 128 + 2 * (d - 256);
        const float* W = WhhL + (size_t)G4 * 256;
        return pk(W[(size_t)j * 256 + k], W[(size_t)j * 256 + k + 1]); }
}

// ---------------- prep kernels (run every call; deterministic) ----------------
__global__ void pack_reg(const float* __restrict__ Whh0, const float* __restrict__ WihL,
                         const float* __restrict__ WhhL, uint32_t* __restrict__ wsd) {
    int id = blockIdx.x * blockDim.x + threadIdx.x;
    if (id >= 8 * 320 * 256) return;
    int lane = id & 255, rest = id >> 8;
    int d = rest % 320, w = rest / 320;
    wsd[OFF_WREG + ((size_t)(w * 320 + d)) * 256 + lane] = fetch_wdw(w, lane, d, Whh0, WihL, WhhL);
}

__global__ void pack_misc(const float* __restrict__ Wih0,
                          const float* __restrict__ bih0, const float* __restrict__ bhh0,
                          const float* __restrict__ WihL,
                          const float* __restrict__ bihL, const float* __restrict__ bhhL,
                          uint32_t* __restrict__ wsd) {
    int id = blockIdx.x * blockDim.x + threadIdx.x;
    if (id >= 8 * 12 * 256) return;
    int lane = id & 255, rest = id >> 8;
    int p = rest % 12, w = rest / 12;
    int c = lane >> 1, half = lane & 1;
    int j = (c >> 5) * 256 + w * 32 + (c & 31);
    float v = 0.0f;
    if (half == 0) {
        switch (p) {
            case 0: v = bih0[j] + bhh0[j]; break;
            case 1: v = Wih0[j * 2 + 0]; break;
            case 2: v = Wih0[j * 2 + 1]; break;
            case 3: v = bihL[j] + bhhL[j]; break;
            case 4: v = WihL[(size_t)j * 258 + 0]; break;
            case 5: v = WihL[(size_t)j * 258 + 1]; break;
            case 6: v = bihL[G4 + j] + bhhL[G4 + j]; break;
            case 7: v = WihL[(size_t)G4 * 258 + (size_t)j * 258 + 0]; break;
            case 8: v = WihL[(size_t)G4 * 258 + (size_t)j * 258 + 1]; break;
            default: v = 0.0f;
        }
    }
    ((float*)(wsd + OFF_MISC))[(w * 12 + p) * 256 + lane] = v;
}

__global__ void pack_head(const float* __restrict__ Wg, const float* __restrict__ bg,
                          const float* __restrict__ Ww, const float* __restrict__ bw,
                          uint32_t* __restrict__ wsd) {
    int id = blockIdx.x * blockDim.x + threadIdx.x;
    if (id < 120 * 129) {
        int jo = id / 129, dd = id % 129;
        uint32_t v = 0;
        if (dd < 128) {
            int k = 2 * dd;
            if (jo < 100) v = pk(Wg[(size_t)jo * 258 + 2 + k], Wg[(size_t)jo * 258 + 3 + k]);
            else          v = pk(Ww[(size_t)(jo - 100) * 258 + 2 + k], Ww[(size_t)(jo - 100) * 258 + 3 + k]);
        }
        wsd[OFF_HEADW + id] = v;
    } else if (id < 120 * 129 + 360) {
        int p = id - 120 * 129;
        int jo = p / 3, q = p % 3;
        float v;
        if (jo < 100) v = (q == 0) ? bg[jo] : Wg[(size_t)jo * 258 + (q - 1)];
        else          v = (q == 0) ? bw[jo - 100] : Ww[(size_t)(jo - 100) * 258 + (q - 1)];
        ((float*)(wsd + OFF_HXB))[p] = v;
    }
}

__global__ void zero_cnt(uint32_t* __restrict__ wsd) {
    int id = blockIdx.x * blockDim.x + threadIdx.x;
    if (id < 32 * 48) wsd[OFF_CNT + id] = 0;
}

// ---------------- group sync primitives ----------------
__device__ __forceinline__ void group_post(uint32_t* c) {
    __syncthreads();   // compiler drains vmcnt before s_barrier -> all stores done
    if (threadIdx.x == 0) {
        __threadfence();
        __hip_atomic_fetch_add(c, 1u, __ATOMIC_RELEASE, __HIP_MEMORY_SCOPE_AGENT);
    }
}
__device__ __forceinline__ void group_wait(uint32_t* c, uint32_t target) {
    if (threadIdx.x == 0) {
        while (__hip_atomic_load(c, __ATOMIC_RELAXED, __HIP_MEMORY_SCOPE_AGENT) < target)
            __builtin_amdgcn_s_sleep(2);
    }
    __syncthreads();
    __threadfence();   // acquire: invalidate caches before reading hbuf
}

// ---------------- main persistent kernel ----------------
#define GATE_INIT(PB, PXA, PXB)                                               \
    float a0 = (PB) + x_s[par][0][0] * (PXA) + x_s[par][0][1] * (PXB);        \
    float a1 = (PB) + x_s[par][1][0] * (PXA) + x_s[par][1][1] * (PXB);        \
    float a2 = (PB) + x_s[par][2][0] * (PXA) + x_s[par][2][1] * (PXB);        \
    float a3 = (PB) + x_s[par][3][0] * (PXA) + x_s[par][3][1] * (PXB);

#define GATE_ACCUM(WB, HL)                                                    \
    { _Pragma("unroll")                                                       \
      for (int d4 = 0; d4 < 16; ++d4) {                                       \
        uint4 h0v = *(const uint4*)&h_lds[HL][0][hoff + d4 * 4];              \
        uint4 h1v = *(const uint4*)&h_lds[HL][1][hoff + d4 * 4];              \
        uint4 h2v = *(const uint4*)&h_lds[HL][2][hoff + d4 * 4];              \
        uint4 h3v = *(const uint4*)&h_lds[HL][3][hoff + d4 * 4];              \
        _Pragma("unroll")                                                     \
        for (int kk = 0; kk < 4; ++kk) {                                      \
          uint32_t wv = wr[(WB) + d4 * 4 + kk];                               \
          a0 = dot2f(wv, ((const uint32_t*)&h0v)[kk], a0);                    \
          a1 = dot2f(wv, ((const uint32_t*)&h1v)[kk], a1);                    \
          a2 = dot2f(wv, ((const uint32_t*)&h2v)[kk], a2);                    \
          a3 = dot2f(wv, ((const uint32_t*)&h3v)[kk], a3);                    \
        } } }

#define COMBINE_STORE()                                                       \
    a0 += __shfl_xor(a0, 1); a1 += __shfl_xor(a1, 1);                         \
    a2 += __shfl_xor(a2, 1); a3 += __shfl_xor(a3, 1);                         \
    if (!(tid & 1)) {                                                         \
        int cc_ = tid >> 1;                                                   \
        g_s[0][cc_] = a0; g_s[1][cc_] = a1; g_s[2][cc_] = a2; g_s[3][cc_] = a3; \
    }

#define UPDATE_STORE(CS, LIDX)                                                \
    __syncthreads();                                                          \
    if (tid < 128) {                                                          \
        float gi = g_s[ur][un],      gf = g_s[ur][32 + un];                   \
        float gg = g_s[ur][64 + un], go = g_s[ur][96 + un];                   \
        float cc = sigf(gf) * (CS) + sigf(gi) * tanhfast(gg);                 \
        float hh = sigf(go) * tanhfast(cc);                                   \
        (CS) = cc;                                                            \
        ((__half*)(hb + ((LIDX) * 2 + par) * 512))[ur * 256 + w * 32 + un] =  \
            __float2half(hh);                                                 \
    }                                                                         \
    group_post(cnt + (LIDX) * 16);

#define READ_H(LIDX, PAR)                                                     \
    { int rr = tid >> 6, ii = tid & 63;                                       \
      uint2 v = *(const uint2*)(hb + (((LIDX) * 2 + (PAR)) * 4 + rr) * 128 + 2 * ii); \
      *(uint2*)&h_lds[LIDX][rr][2 * ii] = v; }                                \
    __syncthreads();

#define HEAD_COMPUTE(TT, PP)                                                  \
    if (w < 4) {                                                              \
        if (tid < 240) {                                                      \
            int jo = tid >> 1, kh = tid & 1;                                  \
            float acc = (kh == 0) ? (hxb_s[jo * 3] + x_s[PP][w][0] * hxb_s[jo * 3 + 1] \
                                     + x_s[PP][w][1] * hxb_s[jo * 3 + 2]) : 0.0f; \
            _Pragma("unroll")                                                 \
            for (int d = 0; d < 64; ++d)                                      \
                acc = dot2f(headw_s[jo * 129 + kh * 64 + d],                  \
                            h_lds[2][w][kh * 64 + d], acc);                   \
            acc += __shfl_xor(acc, 1);                                        \
            if (!kh) {                                                        \
                if (jo < 100) out[((size_t)(b0 + w) * T_STEPS + (TT)) * NOUT + jo] = acc; \
                else          wl_s[jo - 100] = acc;                           \
            }                                                                 \
        }                                                                     \
        __syncthreads();                                                      \
        if (tid == 0) {                                                       \
            float mx = -1e30f;                                                \
            _Pragma("unroll")                                                 \
            for (int m = 0; m < NW; ++m) mx = fmaxf(mx, wl_s[m]);             \
            float ssum = 0.0f, ee[NW];                                        \
            _Pragma("unroll")                                                 \
            for (int m = 0; m < NW; ++m) { ee[m] = __expf(wl_s[m] - mx); ssum += ee[m]; } \
            float inv = 1.0f / ssum;                                          \
            size_t bo_ = GOFF + ((size_t)(b0 + w) * T_STEPS + (TT)) * NW;     \
            _Pragma("unroll")                                                 \
            for (int m = 0; m < NW; ++m) out[bo_ + m] = ee[m] * inv;          \
        }                                                                     \
    }

template <bool WSPACK>
__global__ __launch_bounds__(NTHM, 1)
void lstm_persist(const float* __restrict__ x, uint32_t* __restrict__ wsd,
                  float* __restrict__ out,
                  const float* __restrict__ Whh0, const float* __restrict__ WihL,
                  const float* __restrict__ WhhL) {
    __shared__ uint32_t headw_s[120 * 129];
    __shared__ uint32_t h_lds[3][4][128];   // fp16 pairs; h[l][row][kdw]
    __shared__ float    g_s[4][128];
    __shared__ float    x_s[2][4][2];
    __shared__ float    wl_s[NW];
    __shared__ float    hxb_s[360];

    const int tid = threadIdx.x;
    const int bid = blockIdx.x;
    const int g = bid & 31;        // group: same (bid%8) for all 8 slices -> same XCD (heuristic)
    const int w = bid >> 5;        // slice 0..7
    const int b0 = g * 4;
    const int hoff = (tid & 1) * 64;
    const int un = tid & 31, ur = tid >> 5;

    uint32_t* hb  = wsd + OFF_HBUF + (size_t)g * 3072;
    uint32_t* cnt = wsd + OFF_CNT + g * 48;

    // ---- load weight slice into registers (persistent) ----
    uint32_t wr[320];
    if (WSPACK) {
        const uint32_t* wbase = wsd + OFF_WREG + (size_t)w * 320 * 256 + tid;
#pragma unroll
        for (int d = 0; d < 320; ++d) wr[d] = wbase[(size_t)d * 256];
    } else {
#pragma unroll
        for (int d = 0; d < 320; ++d) wr[d] = fetch_wdw(w, tid, d, Whh0, WihL, WhhL);
    }
    const float* mb = (const float*)(wsd + OFF_MISC) + (w * 12) * 256 + tid;
    const float pb0 = mb[0],       px00 = mb[256],     px01 = mb[512];
    const float pb1 = mb[3 * 256], px10 = mb[4 * 256], px11 = mb[5 * 256];
    const float pb2 = mb[6 * 256], px20 = mb[7 * 256], px21 = mb[8 * 256];

    // ---- init LDS ----
    for (int i = tid; i < 3 * 4 * 128; i += NTHM) (&h_lds[0][0][0])[i] = 0u;
    for (int i = tid; i < 120 * 129; i += NTHM)   headw_s[i] = wsd[OFF_HEADW + i];
    for (int i = tid; i < 360; i += NTHM)         hxb_s[i] = ((const float*)(wsd + OFF_HXB))[i];
    float cs0 = 0.0f, cs1 = 0.0f, cs2 = 0.0f;

    float xpre = 0.0f;
    if (tid < 8) xpre = x[((size_t)(b0 + (tid >> 1)) * T_STEPS + 0) * 2 + (tid & 1)];
    __syncthreads();

    for (int t = 0; t < T_STEPS; ++t) {
        const int par = t & 1;
        if (tid < 8) x_s[par][tid >> 1][tid & 1] = xpre;
        __syncthreads();

        // ---- layer 0 (uses h_lds[0] = h0@t-1, stable since last L1 read) ----
        {
            GATE_INIT(pb0, px00, px01);
            GATE_ACCUM(0, 0);
            COMBINE_STORE();
            UPDATE_STORE(cs0, 0);
        }

        // prefetch x@t+1 (hidden under head/L1 phases)
        if (tid < 8 && t + 1 < T_STEPS)
            xpre = x[((size_t)(b0 + (tid >> 1)) * T_STEPS + (t + 1)) * 2 + (tid & 1)];

        // ---- head(t-1): wait for h2@t-1, read to LDS (all WGs; recur use at L2) ----
        if (t > 0) {
            const int pp = (t - 1) & 1;
            group_wait(cnt + 2 * 16, 8u * (uint32_t)t);
            READ_H(2, pp);
            HEAD_COMPUTE(t - 1, pp);
        }

        // ---- layer 1: needs full h0@t ----
        group_wait(cnt + 0, 8u * (uint32_t)(t + 1));
        READ_H(0, par);
        {
            GATE_INIT(pb1, px10, px11);
            GATE_ACCUM(64, 0);    // skip connection over h0@t
            GATE_ACCUM(128, 1);   // recurrent over h1@t-1
            COMBINE_STORE();
            UPDATE_STORE(cs1, 1);
        }

        // ---- layer 2: needs full h1@t ----
        group_wait(cnt + 16, 8u * (uint32_t)(t + 1));
        READ_H(1, par);
        {
            GATE_INIT(pb2, px20, px21);
            GATE_ACCUM(192, 1);   // skip over h1@t
            GATE_ACCUM(256, 2);   // recurrent over h2@t-1
            COMBINE_STORE();
            UPDATE_STORE(cs2, 2);
        }
    }

    // ---- final head(T-1) ----
    {
        const int pp = (T_STEPS - 1) & 1;
        group_wait(cnt + 2 * 16, 8u * (uint32_t)T_STEPS);
        READ_H(2, pp);
        HEAD_COMPUTE(T_STEPS - 1, pp);
    }
}

extern "C" void kernel_launch(void* const* d_in, const int* in_sizes, int n_in,
                              void* d_out, int out_size, void* d_ws, size_t ws_size,
                              hipStream_t stream) {
    const float* x    = (const float*)d_in[0];
    const float* Wih0 = (const float*)d_in[1];
    const float* Whh0 = (const float*)d_in[2];
    const float* bih0 = (const float*)d_in[3];
    const float* bhh0 = (const float*)d_in[4];
    const float* WihL = (const float*)d_in[5];
    const float* WhhL = (const float*)d_in[6];
    const float* bihL = (const float*)d_in[7];
    const float* bhhL = (const float*)d_in[8];
    const float* Wg   = (const float*)d_in[9];
    const float* bg   = (const float*)d_in[10];
    const float* Ww   = (const float*)d_in[11];
    const float* bw   = (const float*)d_in[12];
    float*    out = (float*)d_out;
    uint32_t* wsd = (uint32_t*)d_ws;
    (void)in_sizes; (void)n_in; (void)out_size;

    const bool wspack = ws_size >= WS_FULL_DW * 4;

    zero_cnt<<<6, 256, 0, stream>>>(wsd);
    pack_misc<<<96, 256, 0, stream>>>(Wih0, bih0, bhh0, WihL, bihL, bhhL, wsd);
    pack_head<<<62, 256, 0, stream>>>(Wg, bg, Ww, bw, wsd);
    if (wspack)
        pack_reg<<<2560, 256, 0, stream>>>(Whh0, WihL, WhhL, wsd);

    dim3 grid(NGROUPS * NSLICE), block(NTHM);
    hipError_t err;
    if (wspack) {
        void* args[] = {(void*)&x, (void*)&wsd, (void*)&out,
                        (void*)&Whh0, (void*)&WihL, (void*)&WhhL};
        err = hipLaunchCooperativeKernel((const void*)lstm_persist<true>,
                                         grid, block, args, 0, stream);
        if (err != hipSuccess)
            lstm_persist<true><<<grid, block, 0, stream>>>(x, wsd, out, Whh0, WihL, WhhL);
    } else {
        void* args[] = {(void*)&x, (void*)&wsd, (void*)&out,
                        (void*)&Whh0, (void*)&WihL, (void*)&WhhL};
        err = hipLaunchCooperativeKernel((const void*)lstm_persist<false>,
                                         grid, block, args, 0, stream);
        if (err != hipSuccess)
            lstm_persist<false><<<grid, block, 0, stream>>>(x, wsd, out, Whh0, WihL, WhhL);
    }
}

// Round 4
// 13842.293 us; speedup vs baseline: 4.9823x; 4.9823x over previous
//
#include <hip/hip_runtime.h>
#include <hip/hip_fp16.h>
#include <stdint.h>

// ---------------- problem constants ----------------
#define T_STEPS 1000
#define BATCH   128
#define HID     256
#define G4      1024
#define NOUT    100
#define NW      20
#define NTHM    512     // threads per WG (8 waves)
#define NGROUPS 16      // batch groups
#define NSLICE  8       // WGs per group (hidden-dim slices of 32 units)
#define BT      8       // batch rows per group

// ---------------- ws layout (dword offsets) ----------------
constexpr int    OFF_HBUF  = 0;                               // [16][3][2][8][128]
constexpr int    OFF_CNT   = OFF_HBUF + NGROUPS * 3 * 2 * 8 * 128;   // 98304: [16][48]
constexpr int    OFF_HEADW = OFF_CNT + NGROUPS * 48;          // 99072: [120][128] fp16-pairs
constexpr int    OFF_HXB   = OFF_HEADW + 120 * 128;           // 114432: [120][3] f32
constexpr int    OFF_MISC  = OFF_HXB + 360;                   // 114792: [8][3][3][128] f32
constexpr int    OFF_WREG  = OFF_MISC + 8 * 3 * 3 * 128;      // 124008: [8][160][512]
constexpr size_t WS_FULL_DW = (size_t)OFF_WREG + 8 * 160 * 512;   // 779,368 dw (~3.0 MB)
constexpr size_t GOFF = (size_t)BATCH * T_STEPS * NOUT;

__device__ __forceinline__ float sigf(float x)     { return 1.0f / (1.0f + __expf(-x)); }
__device__ __forceinline__ float tanhfast(float x) { return 2.0f / (1.0f + __expf(-2.0f * x)) - 1.0f; }

typedef _Float16 h2v __attribute__((ext_vector_type(2)));
__device__ __forceinline__ float dot2f(uint32_t w, uint32_t h, float acc) {
    return __builtin_amdgcn_fdot2(__builtin_bit_cast(h2v, w),
                                  __builtin_bit_cast(h2v, h), acc, false);
}
__device__ __forceinline__ uint32_t pk(float a, float b) {
    __half2 h = __floats2half2_rn(a, b);
    return *reinterpret_cast<uint32_t*>(&h);
}

// Weight element for (slice w, thread tid, reg idx<160). Shared by pack kernel
// and direct-gather fallback. tid -> cg=tid>>3 (col-pair), kq=tid&7 (K-eighth).
// idx = m*32 + cc*16 + d : matrix m in {L0r, L1s, L1r, L2s, L2r}, col c=cg*2+cc,
// k-halfs = kq*32 + 2d.
__device__ __forceinline__ uint32_t fetch_wdw(int w, int tid, int idx,
                                              const float* __restrict__ Whh0,
                                              const float* __restrict__ WihL,
                                              const float* __restrict__ WhhL) {
    int cg = tid >> 3, kq = tid & 7;
    int m = idx >> 5, rem = idx & 31;
    int cc = rem >> 4, d = rem & 15;
    int c = cg * 2 + cc;
    int j = (c >> 5) * 256 + w * 32 + (c & 31);
    int k = kq * 32 + 2 * d;
    switch (m) {
        case 0: return pk(Whh0[(size_t)j * 256 + k], Whh0[(size_t)j * 256 + k + 1]);
        case 1: return pk(WihL[(size_t)j * 258 + 2 + k], WihL[(size_t)j * 258 + 3 + k]);
        case 2: return pk(WhhL[(size_t)j * 256 + k], WhhL[(size_t)j * 256 + k + 1]);
        case 3: { const float* W = WihL + (size_t)G4 * 258;
                  return pk(W[(size_t)j * 258 + 2 + k], W[(size_t)j * 258 + 3 + k]); }
        default:{ const float* W = WhhL + (size_t)G4 * 256;
                  return pk(W[(size_t)j * 256 + k], W[(size_t)j * 256 + k + 1]); }
    }
}

// ---------------- prep kernels ----------------
__global__ void pack_reg(const float* __restrict__ Whh0, const float* __restrict__ WihL,
                         const float* __restrict__ WhhL, uint32_t* __restrict__ wsd) {
    int id = blockIdx.x * blockDim.x + threadIdx.x;
    if (id >= 8 * 160 * 512) return;
    int lane = id & 511, rest = id >> 9;
    int idx = rest % 160, w = rest / 160;
    wsd[OFF_WREG + ((size_t)(w * 160 + idx)) * 512 + lane] =
        fetch_wdw(w, lane, idx, Whh0, WihL, WhhL);
}

__global__ void pack_misc(const float* __restrict__ Wih0,
                          const float* __restrict__ bih0, const float* __restrict__ bhh0,
                          const float* __restrict__ WihL,
                          const float* __restrict__ bihL, const float* __restrict__ bhhL,
                          uint32_t* __restrict__ wsd) {
    int id = blockIdx.x * blockDim.x + threadIdx.x;
    if (id >= 8 * 1152) return;
    int c = id & 127, rest = id >> 7;
    int q = rest % 3; rest /= 3;
    int l = rest % 3, w = rest / 3;
    int j = (c >> 5) * 256 + w * 32 + (c & 31);
    float v;
    if (l == 0)      v = (q == 0) ? bih0[j] + bhh0[j] : Wih0[j * 2 + (q - 1)];
    else if (l == 1) v = (q == 0) ? bihL[j] + bhhL[j] : WihL[(size_t)j * 258 + (q - 1)];
    else             v = (q == 0) ? bihL[G4 + j] + bhhL[G4 + j]
                                  : WihL[(size_t)G4 * 258 + (size_t)j * 258 + (q - 1)];
    ((float*)wsd)[OFF_MISC + (size_t)w * 1152 + (l * 3 + q) * 128 + c] = v;
}

__global__ void pack_head(const float* __restrict__ Wg, const float* __restrict__ bg,
                          const float* __restrict__ Ww, const float* __restrict__ bw,
                          uint32_t* __restrict__ wsd) {
    int id = blockIdx.x * blockDim.x + threadIdx.x;
    if (id < 15360) {
        int jo = id >> 7, d = id & 127, k = 2 * d;
        const float* row = (jo < 100) ? (Wg + (size_t)jo * 258) : (Ww + (size_t)(jo - 100) * 258);
        wsd[OFF_HEADW + id] = pk(row[2 + k], row[3 + k]);
    } else if (id < 15360 + 360) {
        int p = id - 15360, jo = p / 3, q = p % 3;
        const float* row = (jo < 100) ? (Wg + (size_t)jo * 258) : (Ww + (size_t)(jo - 100) * 258);
        float v = (q == 0) ? ((jo < 100) ? bg[jo] : bw[jo - 100]) : row[q - 1];
        ((float*)wsd)[OFF_HXB + p] = v;
    }
}

__global__ void zero_cnt(uint32_t* __restrict__ wsd) {
    int id = blockIdx.x * blockDim.x + threadIdx.x;
    if (id < NGROUPS * 48) wsd[OFF_CNT + id] = 0;
}

// ---------------- main persistent kernel ----------------
// h_lds row layout: 8 kq-blocks of 16 dw padded to 20 dw (banks: kq*20%32 all
// distinct -> the 8 broadcast addresses of each ds_read_b128 are conflict-free).
#define ZACC() { _Pragma("unroll") for (int i = 0; i < 16; ++i) acc[i] = 0.0f; }

#define ACCUM_MAT(MB, HL)                                                      \
    { _Pragma("unroll")                                                        \
      for (int d4 = 0; d4 < 4; ++d4) {                                         \
        uint4 hvv[8];                                                          \
        _Pragma("unroll")                                                      \
        for (int r = 0; r < 8; ++r)                                            \
            hvv[r] = *(const uint4*)&h_lds[HL][r][kq20 + d4 * 4];              \
        _Pragma("unroll")                                                      \
        for (int dd = 0; dd < 4; ++dd) {                                       \
            uint32_t w0 = wr[(MB) + d4 * 4 + dd];                              \
            uint32_t w1 = wr[(MB) + 16 + d4 * 4 + dd];                         \
            _Pragma("unroll")                                                  \
            for (int r = 0; r < 8; ++r) {                                      \
                uint32_t hx = ((const uint32_t*)&hvv[r])[dd];                  \
                acc[r]     = dot2f(w0, hx, acc[r]);                            \
                acc[8 + r] = dot2f(w1, hx, acc[8 + r]);                        \
            } } } }

#define REDUCE_WRITE(LYR)                                                      \
    { _Pragma("unroll")                                                        \
      for (int s = 1; s <= 4; s <<= 1) {                                       \
        _Pragma("unroll")                                                      \
        for (int i = 0; i < 16; ++i) acc[i] += __shfl_xor(acc[i], s, 64);      \
      }                                                                        \
      if (kq == 0) {                                                           \
        _Pragma("unroll")                                                      \
        for (int r = 0; r < 8; ++r) {                                          \
            float x0 = x_s[par][r][0], x1 = x_s[par][r][1];                    \
            float b0v = misc_s[LYR][0][c0] + x0 * misc_s[LYR][1][c0]           \
                      + x1 * misc_s[LYR][2][c0];                               \
            float b1v = misc_s[LYR][0][c1] + x0 * misc_s[LYR][1][c1]           \
                      + x1 * misc_s[LYR][2][c1];                               \
            *(float2*)&g_s[r][c0] = make_float2(acc[r] + b0v, acc[8 + r] + b1v); \
        } } }

#define UPDATE_POST(CS, LIDX)                                                  \
    __syncthreads();                                                           \
    { float hval = 0.0f; int r_ = tid >> 5, n_ = tid & 31;                     \
      if (tid < 256) {                                                         \
        float gi = g_s[r_][n_],      gf = g_s[r_][32 + n_];                    \
        float gg = g_s[r_][64 + n_], go = g_s[r_][96 + n_];                    \
        float cc_ = sigf(gf) * (CS) + sigf(gi) * tanhfast(gg);                 \
        hval = sigf(go) * tanhfast(cc_);                                       \
        (CS) = cc_;                                                            \
      }                                                                        \
      float hnb = __shfl_down(hval, 1);                                        \
      if (tid < 256 && !(n_ & 1)) {                                            \
        uint32_t pkv = pk(hval, hnb);                                          \
        __hip_atomic_store(hbuf + (((LIDX) * 2 + par) * 8 + r_) * 128 + w * 16 + (n_ >> 1), \
                           pkv, __ATOMIC_RELAXED, __HIP_MEMORY_SCOPE_AGENT);   \
      } }                                                                      \
    __syncthreads();                                                           \
    if (tid == 0)                                                              \
        __hip_atomic_fetch_add(cnt + (LIDX) * 16, 1u,                          \
                               __ATOMIC_RELAXED, __HIP_MEMORY_SCOPE_AGENT);

#define WAIT_CNT(LIDX, TGT)                                                    \
    if (tid == 0) {                                                            \
        while (__hip_atomic_load(cnt + (LIDX) * 16, __ATOMIC_RELAXED,          \
                                 __HIP_MEMORY_SCOPE_AGENT) < (TGT))            \
            __builtin_amdgcn_s_sleep(1);                                       \
    }                                                                          \
    __syncthreads();

#define READ_H(LIDX, PAR)                                                      \
    { _Pragma("unroll")                                                        \
      for (int q_ = 0; q_ < 2; ++q_) {                                         \
        int idx_ = tid + q_ * 512;                                             \
        int r_ = idx_ >> 7, dwi = idx_ & 127;                                  \
        uint32_t v = __hip_atomic_load(hbuf + (((LIDX) * 2 + (PAR)) * 8 + r_) * 128 + dwi, \
                                       __ATOMIC_RELAXED, __HIP_MEMORY_SCOPE_AGENT); \
        h_lds[LIDX][r_][(dwi >> 4) * 20 + (dwi & 15)] = v;                     \
      } }                                                                      \
    __syncthreads();

#define HEAD_COMPUTE(TT, PP)                                                   \
    { if (tid < 480) {                                                         \
        int jo = tid >> 2, kq2 = tid & 3;                                      \
        float acch = 0.0f;                                                     \
        _Pragma("unroll")                                                      \
        for (int b_ = 0; b_ < 2; ++b_) {                                       \
            int kqh = kq2 * 2 + b_;                                            \
            _Pragma("unroll")                                                  \
            for (int d4 = 0; d4 < 4; ++d4) {                                   \
                uint4 wv4 = *(const uint4*)&headw_s[jo * 132 + kq2 * 32 + b_ * 16 + d4 * 4]; \
                uint4 hv4 = *(const uint4*)&h_lds[2][w][kqh * 20 + d4 * 4];    \
                acch = dot2f(wv4.x, hv4.x, acch); acch = dot2f(wv4.y, hv4.y, acch); \
                acch = dot2f(wv4.z, hv4.z, acch); acch = dot2f(wv4.w, hv4.w, acch); \
            } }                                                                \
        acch += __shfl_xor(acch, 1, 64); acch += __shfl_xor(acch, 2, 64);      \
        if (kq2 == 0) {                                                        \
            float xa = x_s[PP][w][0], xb = x_s[PP][w][1];                      \
            acch += hxb_s[jo * 3] + xa * hxb_s[jo * 3 + 1] + xb * hxb_s[jo * 3 + 2]; \
            if (jo < NOUT) out[((size_t)(b0 + w) * T_STEPS + (TT)) * NOUT + jo] = acch; \
            else           wl_s[jo - NOUT] = acch;                             \
        } }                                                                    \
      __syncthreads();                                                         \
      if (tid == 0) {                                                          \
        float mx = -1e30f;                                                     \
        _Pragma("unroll")                                                      \
        for (int m_ = 0; m_ < NW; ++m_) mx = fmaxf(mx, wl_s[m_]);              \
        float ss = 0.0f, ee[NW];                                               \
        _Pragma("unroll")                                                      \
        for (int m_ = 0; m_ < NW; ++m_) { ee[m_] = __expf(wl_s[m_] - mx); ss += ee[m_]; } \
        float inv = 1.0f / ss;                                                 \
        size_t bo = GOFF + ((size_t)(b0 + w) * T_STEPS + (TT)) * NW;           \
        _Pragma("unroll")                                                      \
        for (int m_ = 0; m_ < NW; ++m_) out[bo + m_] = ee[m_] * inv;           \
      } }

template <bool WSPACK>
__global__ __launch_bounds__(NTHM, 2)
void lstm_persist(const float* __restrict__ x, uint32_t* __restrict__ wsd,
                  float* __restrict__ out,
                  const float* __restrict__ Whh0, const float* __restrict__ WihL,
                  const float* __restrict__ WhhL) {
    __shared__ uint32_t headw_s[120 * 132];   // padded stride 132
    __shared__ uint32_t h_lds[3][8][160];     // 8 kq-blocks x (16+4) dw per row
    __shared__ float    g_s[8][128];
    __shared__ float    misc_s[3][3][128];
    __shared__ float    x_s[2][8][2];
    __shared__ float    wl_s[NW];
    __shared__ float    hxb_s[360];

    const int tid = threadIdx.x;
    const int bid = blockIdx.x;
    const int g = bid & (NGROUPS - 1);   // slices of a group share bid%8 -> same XCD
    const int w = bid >> 4;              // slice 0..7
    const int b0 = g * BT;
    const int cg = tid >> 3, kq = tid & 7;
    const int c0 = cg * 2, c1 = c0 + 1;
    const int kq20 = kq * 20;

    uint32_t* hbuf = wsd + OFF_HBUF + (size_t)g * 6144;
    uint32_t* cnt  = wsd + OFF_CNT + g * 48;
    const float* wsf = (const float*)wsd;

    // ---- persistent weight slice: 160 dwords/thread in VGPRs ----
    uint32_t wr[160];
    if (WSPACK) {
        const uint32_t* wb = wsd + OFF_WREG + (size_t)w * 160 * 512 + tid;
#pragma unroll
        for (int i = 0; i < 160; ++i) wr[i] = wb[(size_t)i * 512];
    } else {
#pragma unroll
        for (int i = 0; i < 160; ++i) wr[i] = fetch_wdw(w, tid, i, Whh0, WihL, WhhL);
    }

    // ---- init LDS ----
    for (int i = tid; i < 3 * 8 * 160; i += NTHM) (&h_lds[0][0][0])[i] = 0u;
    for (int i = tid; i < 15360; i += NTHM) headw_s[(i >> 7) * 132 + (i & 127)] = wsd[OFF_HEADW + i];
    for (int i = tid; i < 360; i += NTHM) hxb_s[i] = wsf[OFF_HXB + i];
    for (int i = tid; i < 1152; i += NTHM) (&misc_s[0][0][0])[i] = wsf[OFF_MISC + (size_t)w * 1152 + i];
    float cs0 = 0.0f, cs1 = 0.0f, cs2 = 0.0f;
    float xpre = 0.0f;
    if (tid < 16) xpre = x[((size_t)(b0 + (tid >> 1)) * T_STEPS + 0) * 2 + (tid & 1)];
    __syncthreads();

    float acc[16];

    for (int t = 0; t < T_STEPS; ++t) {
        const int par = t & 1;
        if (tid < 16) x_s[par][tid >> 1][tid & 1] = xpre;
        __syncthreads();

        // ---- layer 0 (h_lds[0] = h0@t-1) ----
        ZACC();
        ACCUM_MAT(0, 0)
        REDUCE_WRITE(0)
        UPDATE_POST(cs0, 0)

        if (tid < 16 && t + 1 < T_STEPS)
            xpre = x[((size_t)(b0 + (tid >> 1)) * T_STEPS + (t + 1)) * 2 + (tid & 1)];

        // ---- head(t-1): wait h2@t-1 (posted end of step t-1 -> ~no wait) ----
        if (t > 0) {
            WAIT_CNT(2, 8u * (uint32_t)t)
            READ_H(2, (t - 1) & 1)
            HEAD_COMPUTE(t - 1, (t - 1) & 1)
        }

        // ---- layer 1: needs full h0@t ----
        WAIT_CNT(0, 8u * (uint32_t)(t + 1))
        READ_H(0, par)
        ZACC();
        ACCUM_MAT(32, 0)     // skip connection over h0@t
        ACCUM_MAT(64, 1)     // recurrent over h1@t-1
        REDUCE_WRITE(1)
        UPDATE_POST(cs1, 1)

        // ---- layer 2: needs full h1@t ----
        WAIT_CNT(1, 8u * (uint32_t)(t + 1))
        READ_H(1, par)
        ZACC();
        ACCUM_MAT(96, 1)     // skip over h1@t
        ACCUM_MAT(128, 2)    // recurrent over h2@t-1 (read at head phase)
        REDUCE_WRITE(2)
        UPDATE_POST(cs2, 2)
    }

    // ---- final head(T-1) ----
    WAIT_CNT(2, 8u * (uint32_t)T_STEPS)
    READ_H(2, (T_STEPS - 1) & 1)
    HEAD_COMPUTE(T_STEPS - 1, (T_STEPS - 1) & 1)
}

extern "C" void kernel_launch(void* const* d_in, const int* in_sizes, int n_in,
                              void* d_out, int out_size, void* d_ws, size_t ws_size,
                              hipStream_t stream) {
    const float* x    = (const float*)d_in[0];
    const float* Wih0 = (const float*)d_in[1];
    const float* Whh0 = (const float*)d_in[2];
    const float* bih0 = (const float*)d_in[3];
    const float* bhh0 = (const float*)d_in[4];
    const float* WihL = (const float*)d_in[5];
    const float* WhhL = (const float*)d_in[6];
    const float* bihL = (const float*)d_in[7];
    const float* bhhL = (const float*)d_in[8];
    const float* Wg   = (const float*)d_in[9];
    const float* bg   = (const float*)d_in[10];
    const float* Ww   = (const float*)d_in[11];
    const float* bw   = (const float*)d_in[12];
    float*    out = (float*)d_out;
    uint32_t* wsd = (uint32_t*)d_ws;
    (void)in_sizes; (void)n_in; (void)out_size;

    const bool wspack = ws_size >= WS_FULL_DW * 4;

    zero_cnt<<<3, 256, 0, stream>>>(wsd);
    pack_misc<<<36, 256, 0, stream>>>(Wih0, bih0, bhh0, WihL, bihL, bhhL, wsd);
    pack_head<<<62, 256, 0, stream>>>(Wg, bg, Ww, bw, wsd);
    if (wspack)
        pack_reg<<<2560, 256, 0, stream>>>(Whh0, WihL, WhhL, wsd);

    dim3 grid(NGROUPS * NSLICE), block(NTHM);
    if (wspack) {
        void* args[] = {(void*)&x, (void*)&wsd, (void*)&out,
                        (void*)&Whh0, (void*)&WihL, (void*)&WhhL};
        hipError_t err = hipLaunchCooperativeKernel((const void*)lstm_persist<true>,
                                                    grid, block, args, 0, stream);
        if (err != hipSuccess)
            lstm_persist<true><<<grid, block, 0, stream>>>(x, wsd, out, Whh0, WihL, WhhL);
    } else {
        void* args[] = {(void*)&x, (void*)&wsd, (void*)&out,
                        (void*)&Whh0, (void*)&WihL, (void*)&WhhL};
        hipError_t err = hipLaunchCooperativeKernel((const void*)lstm_persist<false>,
                                                    grid, block, args, 0, stream);
        if (err != hipSuccess)
            lstm_persist<false><<<grid, block, 0, stream>>>(x, wsd, out, Whh0, WihL, WhhL);
    }
}

// Round 5
// 8757.355 us; speedup vs baseline: 7.8753x; 1.5806x over previous
//
#include <hip/hip_runtime.h>
#include <hip/hip_fp16.h>
#include <stdint.h>

// ---------------- problem constants ----------------
#define T_STEPS 1000
#define BATCH   128
#define HID     256
#define G4      1024
#define NOUT    100
#define NW      20
#define NTHM    512     // threads per WG (8 waves)
#define NGROUPS 16      // batch groups (8 rows each)
#define NSLICE  16      // WGs per group; slice = 16 hidden units = 64 gate cols
#define BT      8

// ---------------- ws layout (dword offsets) ----------------
constexpr int    OFF_HBUF  = 0;                                  // [16][3][2][8][128] dw (u64-accessed)
constexpr int    OFF_CNT   = OFF_HBUF + NGROUPS * 3 * 2 * 8 * 128;   // 98304: [16][48]
constexpr int    OFF_HEADW = OFF_CNT + NGROUPS * 48;             // 99072: [120][128] fp16-pairs
constexpr int    OFF_HXB   = OFF_HEADW + 120 * 128;              // 114432: [120][3] f32
constexpr int    OFF_MISC  = OFF_HXB + 360;                      // 114792: [16][9][64] f32
constexpr int    OFF_WREG  = OFF_MISC + 16 * 9 * 64;             // 124008: [16][80][512]
constexpr size_t WS_FULL_DW = (size_t)OFF_WREG + 16 * 80 * 512;  // 779,368 dw ≈ 3.12 MB
constexpr size_t GOFF = (size_t)BATCH * T_STEPS * NOUT;

__device__ __forceinline__ float sigf(float x)     { return 1.0f / (1.0f + __expf(-x)); }
__device__ __forceinline__ float tanhfast(float x) { return 2.0f / (1.0f + __expf(-2.0f * x)) - 1.0f; }

typedef _Float16 h2v __attribute__((ext_vector_type(2)));
__device__ __forceinline__ float dot2f(uint32_t w, uint32_t h, float acc) {
    return __builtin_amdgcn_fdot2(__builtin_bit_cast(h2v, w),
                                  __builtin_bit_cast(h2v, h), acc, false);
}
__device__ __forceinline__ uint32_t pk(float a, float b) {
    __half2 h = __floats2half2_rn(a, b);
    return *reinterpret_cast<uint32_t*>(&h);
}

// Weight element for (slice w, thread tid, reg idx<80).
// tid -> c=tid>>3 (local gate col 0..63), kq=tid&7 (K-eighth).
// c -> gate=c>>4, ni=c&15, j = gate*256 + w*16 + ni.
// idx = m*16 + d, m in {L0r, L1s, L1r, L2s, L2r}; k = kq*32 + 2d.
__device__ __forceinline__ uint32_t fetch_wdw(int w, int tid, int idx,
                                              const float* __restrict__ Whh0,
                                              const float* __restrict__ WihL,
                                              const float* __restrict__ WhhL) {
    int c = tid >> 3, kq = tid & 7;
    int j = (c >> 4) * 256 + w * 16 + (c & 15);
    int m = idx >> 4, d = idx & 15;
    int k = kq * 32 + 2 * d;
    switch (m) {
        case 0: return pk(Whh0[(size_t)j * 256 + k], Whh0[(size_t)j * 256 + k + 1]);
        case 1: return pk(WihL[(size_t)j * 258 + 2 + k], WihL[(size_t)j * 258 + 3 + k]);
        case 2: return pk(WhhL[(size_t)j * 256 + k], WhhL[(size_t)j * 256 + k + 1]);
        case 3: { const float* W = WihL + (size_t)G4 * 258;
                  return pk(W[(size_t)j * 258 + 2 + k], W[(size_t)j * 258 + 3 + k]); }
        default:{ const float* W = WhhL + (size_t)G4 * 256;
                  return pk(W[(size_t)j * 256 + k], W[(size_t)j * 256 + k + 1]); }
    }
}

// ---------------- prep kernels ----------------
__global__ void pack_reg(const float* __restrict__ Whh0, const float* __restrict__ WihL,
                         const float* __restrict__ WhhL, uint32_t* __restrict__ wsd) {
    int id = blockIdx.x * blockDim.x + threadIdx.x;
    if (id >= 16 * 80 * 512) return;
    int lane = id & 511, rest = id >> 9;
    int idx = rest % 80, w = rest / 80;
    wsd[OFF_WREG + ((size_t)(w * 80 + idx)) * 512 + lane] =
        fetch_wdw(w, lane, idx, Whh0, WihL, WhhL);
}

__global__ void pack_misc(const float* __restrict__ Wih0,
                          const float* __restrict__ bih0, const float* __restrict__ bhh0,
                          const float* __restrict__ WihL,
                          const float* __restrict__ bihL, const float* __restrict__ bhhL,
                          uint32_t* __restrict__ wsd) {
    int id = blockIdx.x * blockDim.x + threadIdx.x;
    if (id >= 16 * 9 * 64) return;
    int c = id & 63, rest = id >> 6;
    int q = rest % 3; rest /= 3;
    int l = rest % 3, w = rest / 3;
    int j = (c >> 4) * 256 + w * 16 + (c & 15);
    float v;
    if (l == 0)      v = (q == 0) ? bih0[j] + bhh0[j] : Wih0[j * 2 + (q - 1)];
    else if (l == 1) v = (q == 0) ? bihL[j] + bhhL[j] : WihL[(size_t)j * 258 + (q - 1)];
    else             v = (q == 0) ? bihL[G4 + j] + bhhL[G4 + j]
                                  : WihL[(size_t)G4 * 258 + (size_t)j * 258 + (q - 1)];
    ((float*)wsd)[OFF_MISC + w * 576 + (l * 3 + q) * 64 + c] = v;
}

__global__ void pack_head(const float* __restrict__ Wg, const float* __restrict__ bg,
                          const float* __restrict__ Ww, const float* __restrict__ bw,
                          uint32_t* __restrict__ wsd) {
    int id = blockIdx.x * blockDim.x + threadIdx.x;
    if (id < 15360) {
        int jo = id >> 7, d = id & 127, k = 2 * d;
        const float* row = (jo < 100) ? (Wg + (size_t)jo * 258) : (Ww + (size_t)(jo - 100) * 258);
        wsd[OFF_HEADW + id] = pk(row[2 + k], row[3 + k]);
    } else if (id < 15360 + 360) {
        int p = id - 15360, jo = p / 3, q = p % 3;
        const float* row = (jo < 100) ? (Wg + (size_t)jo * 258) : (Ww + (size_t)(jo - 100) * 258);
        float v = (q == 0) ? ((jo < 100) ? bg[jo] : bw[jo - 100]) : row[q - 1];
        ((float*)wsd)[OFF_HXB + p] = v;
    }
}

__global__ void zero_cnt(uint32_t* __restrict__ wsd) {
    int id = blockIdx.x * blockDim.x + threadIdx.x;
    if (id < NGROUPS * 48) wsd[OFF_CNT + id] = 0;
}

// ---------------- main persistent kernel ----------------
#define ZACC() { _Pragma("unroll") for (int i = 0; i < 8; ++i) acc[i] = 0.0f; }

#define ACCUM_MAT(MB, HL)                                                      \
    { _Pragma("unroll")                                                        \
      for (int d4 = 0; d4 < 4; ++d4) {                                         \
        uint4 hv_[8];                                                          \
        _Pragma("unroll")                                                      \
        for (int r = 0; r < 8; ++r)                                            \
            hv_[r] = *(const uint4*)&h_lds[HL][r][kq20 + d4 * 4];              \
        _Pragma("unroll")                                                      \
        for (int dd = 0; dd < 4; ++dd) {                                       \
            uint32_t wv_ = wr[(MB) + d4 * 4 + dd];                             \
            _Pragma("unroll")                                                  \
            for (int r = 0; r < 8; ++r)                                        \
                acc[r] = dot2f(wv_, ((const uint32_t*)&hv_[r])[dd], acc[r]);   \
        } } }

#define REDUCE_WRITE(LYR, XB)                                                  \
    { _Pragma("unroll")                                                        \
      for (int s = 1; s <= 4; s <<= 1) {                                       \
        _Pragma("unroll")                                                      \
        for (int i = 0; i < 8; ++i) acc[i] += __shfl_xor(acc[i], s, 64);       \
      }                                                                        \
      if (kq == 0) {                                                           \
        _Pragma("unroll")                                                      \
        for (int r = 0; r < 8; ++r) {                                          \
            float x0 = x_s[XB][r][0], x1 = x_s[XB][r][1];                      \
            g_s[r][cc] = acc[r] + misc_s[(LYR) * 3][cc]                        \
                       + x0 * misc_s[(LYR) * 3 + 1][cc]                        \
                       + x1 * misc_s[(LYR) * 3 + 2][cc];                       \
        } } }

#define UPDATE_POST(CS, LIDX, PB)                                              \
    __syncthreads();                                                           \
    { int r_ = tid >> 4, n_ = tid & 15; float hval = 0.0f;                     \
      if (tid < 128) {                                                         \
        float gi = g_s[r_][n_],      gf = g_s[r_][16 + n_];                    \
        float gg = g_s[r_][32 + n_], go = g_s[r_][48 + n_];                    \
        float cc_ = sigf(gf) * (CS) + sigf(gi) * tanhfast(gg);                 \
        hval = sigf(go) * tanhfast(cc_);                                       \
        (CS) = cc_;                                                            \
      }                                                                        \
      float h1_ = __shfl_down(hval, 1);                                        \
      float h2_ = __shfl_down(hval, 2);                                        \
      float h3_ = __shfl_down(hval, 3);                                        \
      if (tid < 128 && !(n_ & 3)) {                                            \
        uint64_t pv = (uint64_t)pk(hval, h1_) | ((uint64_t)pk(h2_, h3_) << 32);\
        __hip_atomic_store(hbuf64 + (((LIDX) * 2 + (PB)) * 8 + r_) * 64        \
                               + w * 4 + (n_ >> 2), pv,                        \
                           __ATOMIC_RELAXED, __HIP_MEMORY_SCOPE_AGENT);        \
      } }                                                                      \
    __syncthreads();                                                           \
    if (tid == 0)                                                              \
        __hip_atomic_fetch_add(cnt + (LIDX) * 16, 1u,                          \
                               __ATOMIC_RELAXED, __HIP_MEMORY_SCOPE_AGENT);

#define WAIT_CNT(LIDX, TGT)                                                    \
    if (tid == 0) {                                                            \
        while (__hip_atomic_load(cnt + (LIDX) * 16, __ATOMIC_RELAXED,          \
                                 __HIP_MEMORY_SCOPE_AGENT) < (TGT))            \
            __builtin_amdgcn_s_sleep(1);                                       \
    }                                                                          \
    __syncthreads();

#define READ_H(LIDX, PB)                                                       \
    { int r_ = tid >> 6, p_ = tid & 63;                                        \
      uint64_t v = __hip_atomic_load(hbuf64 + (((LIDX) * 2 + (PB)) * 8 + r_) * 64 + p_, \
                                     __ATOMIC_RELAXED, __HIP_MEMORY_SCOPE_AGENT); \
      int dwi = 2 * p_;                                                        \
      *(uint64_t*)&h_lds[LIDX][r_][(dwi >> 4) * 20 + (dwi & 15)] = v; }        \
    __syncthreads();

#define HEAD_COMPUTE(TT, XA, XB_)                                              \
    { if (tid < 240) {                                                         \
        int jol = tid >> 2, kq2 = tid & 3;                                     \
        int jo = joBase + jol;                                                 \
        float acch = 0.0f;                                                     \
        _Pragma("unroll")                                                      \
        for (int b_ = 0; b_ < 2; ++b_) {                                       \
            int kqh = kq2 * 2 + b_;                                            \
            _Pragma("unroll")                                                  \
            for (int d4 = 0; d4 < 4; ++d4) {                                   \
                uint4 wv4 = *(const uint4*)&headw_s[jo * 132 + kq2 * 32 + b_ * 16 + d4 * 4]; \
                uint4 hv4 = *(const uint4*)&h_lds[2][hrow][kqh * 20 + d4 * 4]; \
                acch = dot2f(wv4.x, hv4.x, acch); acch = dot2f(wv4.y, hv4.y, acch); \
                acch = dot2f(wv4.z, hv4.z, acch); acch = dot2f(wv4.w, hv4.w, acch); \
            } }                                                                \
        acch += __shfl_xor(acch, 1, 64); acch += __shfl_xor(acch, 2, 64);      \
        if (kq2 == 0) {                                                        \
            acch += hxb_s[jo * 3] + (XA) * hxb_s[jo * 3 + 1] + (XB_) * hxb_s[jo * 3 + 2]; \
            if (jo < NOUT) out[((size_t)(b0 + hrow) * T_STEPS + (TT)) * NOUT + jo] = acch; \
            else           wl_s[jo - NOUT] = acch;                             \
        } }                                                                    \
      __syncthreads();                                                         \
      if (doSm && tid == 0) {                                                  \
        float mx = -1e30f;                                                     \
        _Pragma("unroll")                                                      \
        for (int m_ = 0; m_ < NW; ++m_) mx = fmaxf(mx, wl_s[m_]);              \
        float ss = 0.0f, ee[NW];                                               \
        _Pragma("unroll")                                                      \
        for (int m_ = 0; m_ < NW; ++m_) { ee[m_] = __expf(wl_s[m_] - mx); ss += ee[m_]; } \
        float inv = 1.0f / ss;                                                 \
        size_t bo = GOFF + ((size_t)(b0 + hrow) * T_STEPS + (TT)) * NW;        \
        _Pragma("unroll")                                                      \
        for (int m_ = 0; m_ < NW; ++m_) out[bo + m_] = ee[m_] * inv;           \
      } }

template <bool WSPACK>
__global__ __launch_bounds__(NTHM, 2)
void lstm_persist(const float* __restrict__ x, uint32_t* __restrict__ wsd,
                  float* __restrict__ out,
                  const float* __restrict__ Whh0, const float* __restrict__ WihL,
                  const float* __restrict__ WhhL) {
    __shared__ uint32_t headw_s[120 * 132];   // padded stride 132
    __shared__ uint32_t h_lds[3][8][160];     // 8 kq-blocks x (16+4) dw per row
    __shared__ float    g_s[8][64];
    __shared__ float    misc_s[9][64];
    __shared__ float    x_s[2][8][2];
    __shared__ float    wl_s[NW];
    __shared__ float    hxb_s[360];

    const int tid = threadIdx.x;
    const int bid = blockIdx.x;
    const int g = bid & (NGROUPS - 1);   // all slices of a group share bid%16 -> same bid%8
    const int w = bid >> 4;              // slice 0..15
    const int b0 = g * BT;
    const int cc = tid >> 3, kq = tid & 7;
    const int kq20 = kq * 20;
    const int hrow = w & 7;
    const int joBase = (w >> 3) * 60;
    const bool doSm = (w >= 8);

    uint64_t* hbuf64 = (uint64_t*)(wsd + OFF_HBUF) + (size_t)g * 3072;
    uint32_t* cnt    = wsd + OFF_CNT + g * 48;
    const float* wsf = (const float*)wsd;

    // ---- persistent weight slice: 80 dwords/thread in VGPRs ----
    uint32_t wr[80];
    if (WSPACK) {
        const uint32_t* wb = wsd + OFF_WREG + (size_t)w * 80 * 512 + tid;
#pragma unroll
        for (int i = 0; i < 80; ++i) wr[i] = wb[(size_t)i * 512];
    } else {
#pragma unroll
        for (int i = 0; i < 80; ++i) wr[i] = fetch_wdw(w, tid, i, Whh0, WihL, WhhL);
    }

    // ---- init LDS ----
    for (int i = tid; i < 3 * 8 * 160; i += NTHM) (&h_lds[0][0][0])[i] = 0u;
    for (int i = tid; i < 15360; i += NTHM) headw_s[(i >> 7) * 132 + (i & 127)] = wsd[OFF_HEADW + i];
    for (int i = tid; i < 360; i += NTHM) hxb_s[i] = wsf[OFF_HXB + i];
    for (int i = tid; i < 576; i += NTHM) (&misc_s[0][0])[i] = wsf[OFF_MISC + w * 576 + i];
    float cs0 = 0.0f, cs1 = 0.0f, cs2 = 0.0f;
    float xpre = 0.0f;
    if (tid < 16) {
        x_s[0][tid >> 1][tid & 1] = x[((size_t)(b0 + (tid >> 1)) * T_STEPS + 0) * 2 + (tid & 1)];
        xpre = x[((size_t)(b0 + (tid >> 1)) * T_STEPS + 1) * 2 + (tid & 1)];
    }
    __syncthreads();

    float acc[8];

    // ---- prologue: L0@0 (h0@-1 = 0), post h0@0 into buffer 0 ----
    ZACC(); ACCUM_MAT(0, 0) REDUCE_WRITE(0, 0) UPDATE_POST(cs0, 0, 0)

    for (int t = 0; t < T_STEPS; ++t) {
        const int par = t & 1, nxt = par ^ 1;

        // save x@t-1 for head (buffer about to be overwritten), then stage x@t+1
        float xh0 = x_s[nxt][hrow][0], xh1 = x_s[nxt][hrow][1];
        __syncthreads();
        if (tid < 16) {
            x_s[nxt][tid >> 1][tid & 1] = xpre;
            if (t + 2 < T_STEPS)
                xpre = x[((size_t)(b0 + (tid >> 1)) * T_STEPS + (t + 2)) * 2 + (tid & 1)];
        }
        __syncthreads();

        // ---- phase 1: h0@t (posted 2 phases ago -> ~no wait) ----
        WAIT_CNT(0, (uint32_t)(NSLICE * (t + 1)))
        READ_H(0, par)

        // ---- phase 2: L1@t = skip(h0@t) + recur(h1@t-1) ----
        ZACC(); ACCUM_MAT(16, 0) ACCUM_MAT(32, 1)
        REDUCE_WRITE(1, par) UPDATE_POST(cs1, 1, par)

        // ---- phase 3: L0@t+1 (h0@t already in LDS; no wait) ----
        if (t + 1 < T_STEPS) {
            ZACC(); ACCUM_MAT(0, 0)
            REDUCE_WRITE(0, nxt) UPDATE_POST(cs0, 0, nxt)
        }

        // ---- phase 4: head@t-1 (h2@t-1 posted last iter -> ~no wait) ----
        if (t > 0) {
            WAIT_CNT(2, (uint32_t)(NSLICE * t))
            READ_H(2, nxt)
            HEAD_COMPUTE(t - 1, xh0, xh1)
        }

        // ---- phase 5: h1@t (wait partially hidden by phases 3-4) ----
        WAIT_CNT(1, (uint32_t)(NSLICE * (t + 1)))
        READ_H(1, par)

        // ---- phase 6: L2@t = skip(h1@t) + recur(h2@t-1) ----
        ZACC(); ACCUM_MAT(48, 1) ACCUM_MAT(64, 2)
        REDUCE_WRITE(2, par) UPDATE_POST(cs2, 2, par)
    }

    // ---- epilogue: head@T-1 ----
    WAIT_CNT(2, (uint32_t)(NSLICE * T_STEPS))
    READ_H(2, (T_STEPS - 1) & 1)
    {
        float xh0 = x_s[(T_STEPS - 1) & 1][hrow][0];
        float xh1 = x_s[(T_STEPS - 1) & 1][hrow][1];
        HEAD_COMPUTE(T_STEPS - 1, xh0, xh1)
    }
}

extern "C" void kernel_launch(void* const* d_in, const int* in_sizes, int n_in,
                              void* d_out, int out_size, void* d_ws, size_t ws_size,
                              hipStream_t stream) {
    const float* x    = (const float*)d_in[0];
    const float* Wih0 = (const float*)d_in[1];
    const float* Whh0 = (const float*)d_in[2];
    const float* bih0 = (const float*)d_in[3];
    const float* bhh0 = (const float*)d_in[4];
    const float* WihL = (const float*)d_in[5];
    const float* WhhL = (const float*)d_in[6];
    const float* bihL = (const float*)d_in[7];
    const float* bhhL = (const float*)d_in[8];
    const float* Wg   = (const float*)d_in[9];
    const float* bg   = (const float*)d_in[10];
    const float* Ww   = (const float*)d_in[11];
    const float* bw   = (const float*)d_in[12];
    float*    out = (float*)d_out;
    uint32_t* wsd = (uint32_t*)d_ws;
    (void)in_sizes; (void)n_in; (void)out_size;

    const bool wspack = ws_size >= WS_FULL_DW * 4;

    zero_cnt<<<3, 256, 0, stream>>>(wsd);
    pack_misc<<<36, 256, 0, stream>>>(Wih0, bih0, bhh0, WihL, bihL, bhhL, wsd);
    pack_head<<<62, 256, 0, stream>>>(Wg, bg, Ww, bw, wsd);
    if (wspack)
        pack_reg<<<2560, 256, 0, stream>>>(Whh0, WihL, WhhL, wsd);

    dim3 grid(NGROUPS * NSLICE), block(NTHM);
    if (wspack) {
        void* args[] = {(void*)&x, (void*)&wsd, (void*)&out,
                        (void*)&Whh0, (void*)&WihL, (void*)&WhhL};
        hipError_t err = hipLaunchCooperativeKernel((const void*)lstm_persist<true>,
                                                    grid, block, args, 0, stream);
        if (err != hipSuccess)
            lstm_persist<true><<<grid, block, 0, stream>>>(x, wsd, out, Whh0, WihL, WhhL);
    } else {
        void* args[] = {(void*)&x, (void*)&wsd, (void*)&out,
                        (void*)&Whh0, (void*)&WihL, (void*)&WhhL};
        hipError_t err = hipLaunchCooperativeKernel((const void*)lstm_persist<false>,
                                                    grid, block, args, 0, stream);
        if (err != hipSuccess)
            lstm_persist<false><<<grid, block, 0, stream>>>(x, wsd, out, Whh0, WihL, WhhL);
    }
}

// Round 6
// 6596.396 us; speedup vs baseline: 10.4552x; 1.3276x over previous
//
#include <hip/hip_runtime.h>
#include <hip/hip_fp16.h>
#include <stdint.h>

// ---------------- problem constants ----------------
#define T_STEPS 1000
#define G4      1024
#define NOUT    100
#define NW      20
#define NTHM    512
#define NGROUPS 16      // batch groups of 8 rows
#define BT      8

// roles per group (16 WGs): 0-3 stage0 (L0 + head), 4-9 stage1, 10-15 stage2
// ---------------- ws layout (dword offsets) ----------------
constexpr int    OFF_HBUF  = 0;                            // [16][3][2][8][128] dw (u64-accessed)
constexpr int    OFF_CNT   = OFF_HBUF + NGROUPS*3*2*8*128; // 98304: [16][96]: PC_l at l*16, AC_l at 48+l*16
constexpr int    OFF_HEADW = OFF_CNT + NGROUPS*96;         // 99840: [120][132] fp16-pair dw
constexpr int    OFF_HXB   = OFF_HEADW + 120*132;          // 115680: [120][3] f32
constexpr int    OFF_MISC  = OFF_HXB + 360;                // 116040: [16 roles][3][4][64] f32
constexpr int    OFF_WREG  = OFF_MISC + 16*768;            // 128328: 1408 slots x 512
constexpr size_t WS_DW     = (size_t)OFF_WREG + 1408*512;  // 849,224 dw ~= 3.4 MB (ws >= 5.28 MB proven r1)
constexpr size_t GOFF      = (size_t)128*1000*100;

__device__ __forceinline__ float sigf(float x)     { return 1.0f / (1.0f + __expf(-x)); }
__device__ __forceinline__ float tanhfast(float x) { return 2.0f / (1.0f + __expf(-2.0f * x)) - 1.0f; }

typedef _Float16 h2v __attribute__((ext_vector_type(2)));
__device__ __forceinline__ float dot2f(uint32_t w, uint32_t h, float acc) {
    return __builtin_amdgcn_fdot2(__builtin_bit_cast(h2v, w),
                                  __builtin_bit_cast(h2v, h), acc, false);
}
__device__ __forceinline__ uint32_t pk(float a, float b) {
    __half2 h = __floats2half2_rn(a, b);
    return *reinterpret_cast<uint32_t*>(&h);
}
// DPP row_shl:N add: lane i += lane i+N (within 16-lane row; OOB -> 0).
// After shl1,shl2,shl4 lanes with (lane&7)==0 hold sum of their 8-lane group.
#define DPP_ADD(v, CTRL)                                                        \
    (v) += __builtin_bit_cast(float, __builtin_amdgcn_update_dpp(                \
              0, __builtin_bit_cast(int, (v)), (CTRL), 0xf, 0xf, true));

__device__ __forceinline__ void role_params(int rw, int& stage, int& idx, int& U, int& u0) {
    if (rw < 4)       { stage = 0; idx = rw;      U = 64;            u0 = 64*rw; }
    else if (rw < 10) { stage = 1; idx = rw - 4;  U = (idx<4)?44:40; u0 = (idx<=4)?44*idx:216; }
    else              { stage = 2; idx = rw - 10; U = (idx<4)?44:40; u0 = (idx<=4)?44*idx:216; }
}
__device__ __forceinline__ int role_off(int rw)   { return rw < 4 ? rw*64 : 256 + (rw-4)*96; }

// weight element for (role rw, thread tid, slot): thread = (cq=tid>>3 -> gate=cq>>4,q=cq&15; kq=tid&7)
// stage0: slot = ul*16+d (ul<4, u=q*4+ul); stage1/2: slot = mm*48+ul*16+d (ul<3, u=q*3+ul)
__device__ __forceinline__ uint32_t fetch_wdw(int rw, int tid, int slot,
                                              const float* __restrict__ Whh0,
                                              const float* __restrict__ WihL,
                                              const float* __restrict__ WhhL) {
    int stage, idx, U, u0; role_params(rw, stage, idx, U, u0);
    int cq = tid >> 3, kq = tid & 7;
    int gate = cq >> 4, q = cq & 15;
    int mm, ul, d, u;
    if (stage == 0) { mm = 0; ul = slot >> 4; d = slot & 15; u = q*4 + ul; }
    else { mm = slot / 48; int rem = slot - mm*48; ul = rem >> 4; d = rem & 15; u = q*3 + ul;
           if (u >= U) return 0u; }
    int j = gate*256 + u0 + u;
    int k = kq*32 + 2*d;
    if (stage == 0) return pk(Whh0[(size_t)j*256 + k], Whh0[(size_t)j*256 + k + 1]);
    const float* Wi = WihL + (size_t)(stage-1)*G4*258;
    const float* Wh = WhhL + (size_t)(stage-1)*G4*256;
    if (mm == 0) return pk(Wi[(size_t)j*258 + 2 + k], Wi[(size_t)j*258 + 3 + k]);
    return pk(Wh[(size_t)j*256 + k], Wh[(size_t)j*256 + k + 1]);
}

// ---------------- prep kernels ----------------
__global__ void pack_wreg(const float* __restrict__ Whh0, const float* __restrict__ WihL,
                          const float* __restrict__ WhhL, uint32_t* __restrict__ wsd) {
    int slot = blockIdx.x % 96, rw = blockIdx.x / 96;   // grid 16*96
    if (rw < 4 && slot >= 64) return;
    wsd[OFF_WREG + (size_t)(role_off(rw) + slot)*512 + threadIdx.x] =
        fetch_wdw(rw, threadIdx.x, slot, Whh0, WihL, WhhL);
}

__global__ void pack_misc(const float* __restrict__ Wih0,
                          const float* __restrict__ bih0, const float* __restrict__ bhh0,
                          const float* __restrict__ WihL,
                          const float* __restrict__ bihL, const float* __restrict__ bhhL,
                          uint32_t* __restrict__ wsd) {
    int id = blockIdx.x * blockDim.x + threadIdx.x;
    if (id >= 16*768) return;
    int rw = id / 768, i = id % 768;
    int qq = i / 256, rem = i % 256, gate = rem / 64, u = rem % 64;
    int stage, idx, U, u0; role_params(rw, stage, idx, U, u0);
    float v = 0.0f;
    if (u < U) {
        int j = gate*256 + u0 + u;
        if (stage == 0)      v = (qq == 0) ? bih0[j] + bhh0[j] : Wih0[j*2 + (qq-1)];
        else if (stage == 1) v = (qq == 0) ? bihL[j] + bhhL[j] : WihL[(size_t)j*258 + (qq-1)];
        else                 v = (qq == 0) ? bihL[G4+j] + bhhL[G4+j]
                                           : WihL[(size_t)G4*258 + (size_t)j*258 + (qq-1)];
    }
    ((float*)wsd)[OFF_MISC + id] = v;
}

__global__ void pack_head(const float* __restrict__ Wg, const float* __restrict__ bg,
                          const float* __restrict__ Ww, const float* __restrict__ bw,
                          uint32_t* __restrict__ wsd) {
    int id = blockIdx.x * blockDim.x + threadIdx.x;
    if (id < 120*132) {
        int jo = id / 132, d = id % 132;
        uint32_t v = 0;
        if (d < 128) {
            int k = 2*d;
            const float* row = (jo < 100) ? (Wg + (size_t)jo*258) : (Ww + (size_t)(jo-100)*258);
            v = pk(row[2+k], row[3+k]);
        }
        wsd[OFF_HEADW + id] = v;
    } else if (id < 120*132 + 360) {
        int p = id - 120*132, jo = p/3, qq = p%3;
        const float* row = (jo < 100) ? (Wg + (size_t)jo*258) : (Ww + (size_t)(jo-100)*258);
        float v = (qq == 0) ? ((jo < 100) ? bg[jo] : bw[jo-100]) : row[qq-1];
        ((float*)wsd)[OFF_HXB + p] = v;
    }
}

__global__ void zero_cnt(uint32_t* __restrict__ wsd) {
    int id = blockIdx.x * blockDim.x + threadIdx.x;
    if (id < NGROUPS*96) wsd[OFF_CNT + id] = 0;
}

// ---------------- main pipeline kernel ----------------
__device__ __forceinline__ void pollCnt(uint32_t* c, uint32_t tgt) {
    int spins = 0;
    while (__hip_atomic_load(c, __ATOMIC_RELAXED, __HIP_MEMORY_SCOPE_AGENT) < tgt) {
        __builtin_amdgcn_s_sleep(1);
        if (++spins > (1 << 24)) break;   // bailout: wrong answer beats a hang
    }
}
__device__ __forceinline__ void bump(uint32_t* c) {
    __hip_atomic_fetch_add(c, 1u, __ATOMIC_RELAXED, __HIP_MEMORY_SCOPE_AGENT);
}

template<int NC, int BASE>
__device__ __forceinline__ void accum_mat(float* acc, const uint32_t (&wr)[96],
                                          const uint32_t* hb, int kq20) {
#pragma unroll
    for (int d4 = 0; d4 < 4; ++d4) {
        uint4 hv[8];
#pragma unroll
        for (int r = 0; r < 8; ++r)
            hv[r] = *(const uint4*)(hb + r*160 + kq20 + d4*4);
#pragma unroll
        for (int dd = 0; dd < 4; ++dd)
#pragma unroll
            for (int c = 0; c < NC; ++c) {
                uint32_t wv = wr[BASE + c*16 + d4*4 + dd];
#pragma unroll
                for (int r = 0; r < 8; ++r)
                    acc[c*8 + r] = dot2f(wv, ((const uint32_t*)&hv[r])[dd], acc[c*8 + r]);
            }
    }
}

#define READH(BUF, L, P)                                                          \
    { int r_ = tid >> 6, i_ = tid & 63;                                           \
      uint64_t v_ = __hip_atomic_load(hbuf64 + (((L)*2 + (P))*8 + r_)*64 + i_,    \
                                      __ATOMIC_RELAXED, __HIP_MEMORY_SCOPE_AGENT);\
      *(uint64_t*)&h_lds[BUF][r_][(i_ >> 3)*20 + ((2*i_) & 15)] = v_; }

#define REDUCE_STORE(NC)                                                          \
    { _Pragma("unroll")                                                           \
      for (int i = 0; i < (NC)*8; ++i) {                                          \
          DPP_ADD(acc[i], 0x101) DPP_ADD(acc[i], 0x102) DPP_ADD(acc[i], 0x104)    \
      }                                                                           \
      if (kq == 0) {                                                              \
          _Pragma("unroll")                                                       \
          for (int c = 0; c < (NC); ++c) {                                        \
              int u_ = q*(NC) + c;                                                \
              if (u_ < U) { _Pragma("unroll")                                     \
                  for (int r = 0; r < 8; ++r) g_s[r][gate][u_] = acc[c*8 + r]; }  \
          } } }

#define UPDATE_STORE(LYR, PAR)                                                    \
    { float hval = 0.0f;                                                          \
      if (uu < U) {                                                               \
          float x0 = x_cur[rr][0], x1 = x_cur[rr][1];                             \
          float gi = g_s[rr][0][uu] + misc_s[0][0][uu] + x0*misc_s[1][0][uu] + x1*misc_s[2][0][uu]; \
          float gf = g_s[rr][1][uu] + misc_s[0][1][uu] + x0*misc_s[1][1][uu] + x1*misc_s[2][1][uu]; \
          float gg = g_s[rr][2][uu] + misc_s[0][2][uu] + x0*misc_s[1][2][uu] + x1*misc_s[2][2][uu]; \
          float go = g_s[rr][3][uu] + misc_s[0][3][uu] + x0*misc_s[1][3][uu] + x1*misc_s[2][3][uu]; \
          float cc_ = sigf(gf)*c_st + sigf(gi)*tanhfast(gg);                      \
          hval = sigf(go)*tanhfast(cc_);  c_st = cc_;                             \
      }                                                                           \
      float h1_ = __shfl_down(hval, 8), h2_ = __shfl_down(hval, 16), h3_ = __shfl_down(hval, 24); \
      if (uu < U && (uu & 3) == 0) {                                              \
          uint64_t pv = (uint64_t)pk(hval, h1_) | ((uint64_t)pk(h2_, h3_) << 32); \
          __hip_atomic_store(hbuf64 + (((LYR)*2 + (PAR))*8 + rr)*64 + ((u0 + uu) >> 2), \
                             pv, __ATOMIC_RELAXED, __HIP_MEMORY_SCOPE_AGENT);     \
      } }

template <bool WSPACK>
__global__ __launch_bounds__(NTHM, 2)
void lstm_pipe(const float* __restrict__ x, uint32_t* __restrict__ wsd,
               float* __restrict__ out,
               const float* __restrict__ Whh0, const float* __restrict__ WihL,
               const float* __restrict__ WhhL) {
    __shared__ __align__(16) uint32_t h_lds[2][8][160];   // 8 kq-blocks of 16 dw padded to 20
    __shared__ float    g_s[8][4][64];
    __shared__ float    misc_s[3][4][64];
    __shared__ float    x_cur[8][2];
    __shared__ float    x_ring[4][8][2];
    __shared__ __align__(16) uint32_t headw_s[30*132];
    __shared__ float    hxb_s[30*3];
    __shared__ float    wl_s[8][NW];

    const int tid = threadIdx.x;
    const int bid = blockIdx.x;
    const int g  = bid & (NGROUPS-1);     // all 16 roles of a group share bid%16 -> same XCD
    const int rw = bid >> 4;              // role 0..15
    int stage, idx, U, u0; role_params(rw, stage, idx, U, u0);
    const int b0 = g * BT;
    const int cq = tid >> 3, kq = tid & 7;
    const int gate = cq >> 4, q = cq & 15;
    const int kq20 = kq * 20;
    const int uu = tid >> 3, rr = tid & 7;   // update task (unit, row)

    uint64_t* hbuf64 = (uint64_t*)(wsd + OFF_HBUF) + (size_t)g * 3072;
    uint32_t* cnt = wsd + OFF_CNT + g * 96;
    const float* wsf = (const float*)wsd;

    // ---- persistent weights ----
    uint32_t wr[96];
    const int nslot = (rw < 4) ? 64 : 96;
    if (WSPACK) {
        const uint32_t* wb = wsd + OFF_WREG + (size_t)role_off(rw)*512 + tid;
#pragma unroll
        for (int i = 0; i < 96; ++i) wr[i] = (i < nslot) ? wb[(size_t)i*512] : 0u;
    } else {
#pragma unroll
        for (int i = 0; i < 96; ++i) wr[i] = (i < nslot) ? fetch_wdw(rw, tid, i, Whh0, WihL, WhhL) : 0u;
    }

    // ---- init LDS ----
    for (int i = tid; i < 2*8*160; i += NTHM) (&h_lds[0][0][0])[i] = 0u;
    for (int i = tid; i < 768;     i += NTHM) (&misc_s[0][0][0])[i] = wsf[OFF_MISC + rw*768 + i];
    if (stage == 0) {
        for (int i = tid; i < 30*132; i += NTHM) headw_s[i] = wsd[OFF_HEADW + idx*30*132 + i];
        for (int i = tid; i < 90;     i += NTHM) hxb_s[i]   = wsf[OFF_HXB + idx*90 + i];
    }
    float c_st = 0.0f;
    __syncthreads();

    float acc[32];

    if (stage == 0) {
        // =========== stage0: L0 (+ head trailing by 3) ===========
        uint32_t* pc0 = cnt + 0,  *ac0 = cnt + 48;
        uint32_t* pc2 = cnt + 32, *ac2 = cnt + 48 + 32;
        for (int t = 0; t <= 1002; ++t) {
            const bool doL0 = (t < T_STEPS);
            const bool doHd = (t >= 3);
            const int th = t - 3, par = t & 1;
            float xv = 0.0f;
            if (doL0 && tid < 16)
                xv = x[((size_t)(b0 + (tid >> 1))*T_STEPS + t)*2 + (tid & 1)];
            if (tid == 0) {
                if (doL0 && t >= 2) pollCnt(ac0, 10u*(t-1));
                if (doL0 && t >= 1) pollCnt(pc0, 4u*t);
                if (doHd)           pollCnt(pc2, 6u*(th+1));
            }
            __syncthreads();
            if (doL0 && t >= 1) READH(0, 0, par ^ 1)    // h0@(t-1)
            if (doHd)           READH(1, 2, th & 1)     // h2@th
            __syncthreads();
            if (tid == 0) { if (doL0 && t >= 1) bump(ac0); if (doHd) bump(ac2); }
            if (doL0) {
#pragma unroll
                for (int i = 0; i < 32; ++i) acc[i] = 0.0f;
                accum_mat<4,0>(acc, wr, &h_lds[0][0][0], kq20);
                REDUCE_STORE(4)
                if (tid < 16) {
                    x_cur[tid >> 1][tid & 1] = xv;
                    x_ring[t & 3][tid >> 1][tid & 1] = xv;
                }
            }
            __syncthreads();
            if (doL0) UPDATE_STORE(0, par)
            __syncthreads();
            if (tid == 0 && doL0) bump(pc0);
            if (doHd) {
                int jol = tid >> 4, rr2 = (tid >> 1) & 7, kh = tid & 1;
                float acch = 0.0f;
                if (jol < 30) {
#pragma unroll
                    for (int blk = 0; blk < 4; ++blk)
#pragma unroll
                        for (int d4 = 0; d4 < 4; ++d4) {
                            uint4 wv = *(const uint4*)&headw_s[jol*132 + kh*64 + blk*16 + d4*4];
                            uint4 hv = *(const uint4*)&h_lds[1][rr2][(kh*4 + blk)*20 + d4*4];
                            acch = dot2f(wv.x, hv.x, acch); acch = dot2f(wv.y, hv.y, acch);
                            acch = dot2f(wv.z, hv.z, acch); acch = dot2f(wv.w, hv.w, acch);
                        }
                }
                acch += __shfl_xor(acch, 1);
                if (jol < 30 && kh == 0) {
                    int jo = idx*30 + jol;
                    float xa = x_ring[th & 3][rr2][0], xb = x_ring[th & 3][rr2][1];
                    acch += hxb_s[jol*3] + xa*hxb_s[jol*3+1] + xb*hxb_s[jol*3+2];
                    if (jo < NOUT) out[((size_t)(b0 + rr2)*T_STEPS + th)*NOUT + jo] = acch;
                    else           wl_s[rr2][jo - NOUT] = acch;
                }
                __syncthreads();
                if (idx == 3 && tid < 8) {
                    int r = tid;
                    float mx = -1e30f;
#pragma unroll
                    for (int m = 0; m < NW; ++m) mx = fmaxf(mx, wl_s[r][m]);
                    float ss = 0.0f, ee[NW];
#pragma unroll
                    for (int m = 0; m < NW; ++m) { ee[m] = __expf(wl_s[r][m] - mx); ss += ee[m]; }
                    float inv = 1.0f / ss;
                    size_t bo = GOFF + ((size_t)(b0 + r)*T_STEPS + th)*NW;
#pragma unroll
                    for (int m = 0; m < NW; ++m) out[bo + m] = ee[m]*inv;
                }
            }
        }
    } else {
        // =========== stage1 / stage2 ===========
        const int IN_L = stage - 1, OWN_L = stage;
        const uint32_t NIN   = (stage == 1) ? 4u : 6u;    // producers of input layer
        const uint32_t RDOWN = (stage == 1) ? 12u : 10u;  // readers of own layer
        uint32_t* pcIn  = cnt + IN_L*16;
        uint32_t* pcOwn = cnt + OWN_L*16;
        uint32_t* acIn  = cnt + 48 + IN_L*16;
        uint32_t* acOwn = cnt + 48 + OWN_L*16;
        for (int t = 0; t < T_STEPS; ++t) {
            const int par = t & 1;
            float xv = 0.0f;
            if (tid < 16)
                xv = x[((size_t)(b0 + (tid >> 1))*T_STEPS + t)*2 + (tid & 1)];
            if (tid == 0) {
                if (t >= 2) pollCnt(acOwn, RDOWN*(uint32_t)(t-1));  // own slot free
                pollCnt(pcIn, NIN*(uint32_t)(t+1));                 // h_in@t ready (aged)
            }
            __syncthreads();
            READH(0, IN_L, par)                       // skip input h_{l-1}@t
            __syncthreads();
            if (tid == 0) bump(acIn);
#pragma unroll
            for (int i = 0; i < 24; ++i) acc[i] = 0.0f;
            accum_mat<3,0>(acc, wr, &h_lds[0][0][0], kq20);   // skip matrix
            if (t >= 1) {
                if (tid == 0) pollCnt(pcOwn, 6u*(uint32_t)t); // own h@(t-1) (posted prev beat)
                __syncthreads();
                READH(1, OWN_L, par ^ 1)
                __syncthreads();
                if (tid == 0) bump(acOwn);
            }
            accum_mat<3,48>(acc, wr, &h_lds[1][0][0], kq20);  // recurrent matrix
            REDUCE_STORE(3)
            if (tid < 16) x_cur[tid >> 1][tid & 1] = xv;
            __syncthreads();
            UPDATE_STORE(OWN_L, par)
            __syncthreads();
            if (tid == 0) bump(pcOwn);
        }
    }
}

extern "C" void kernel_launch(void* const* d_in, const int* in_sizes, int n_in,
                              void* d_out, int out_size, void* d_ws, size_t ws_size,
                              hipStream_t stream) {
    const float* x    = (const float*)d_in[0];
    const float* Wih0 = (const float*)d_in[1];
    const float* Whh0 = (const float*)d_in[2];
    const float* bih0 = (const float*)d_in[3];
    const float* bhh0 = (const float*)d_in[4];
    const float* WihL = (const float*)d_in[5];
    const float* WhhL = (const float*)d_in[6];
    const float* bihL = (const float*)d_in[7];
    const float* bhhL = (const float*)d_in[8];
    const float* Wg   = (const float*)d_in[9];
    const float* bg   = (const float*)d_in[10];
    const float* Ww   = (const float*)d_in[11];
    const float* bw   = (const float*)d_in[12];
    float*    out = (float*)d_out;
    uint32_t* wsd = (uint32_t*)d_ws;
    (void)in_sizes; (void)n_in; (void)out_size;

    const bool wspack = ws_size >= WS_DW * 4;   // proven >= 5.28 MB in r1; guard anyway

    zero_cnt<<<6, 256, 0, stream>>>(wsd);
    pack_misc<<<48, 256, 0, stream>>>(Wih0, bih0, bhh0, WihL, bihL, bhhL, wsd);
    pack_head<<<64, 256, 0, stream>>>(Wg, bg, Ww, bw, wsd);
    if (wspack)
        pack_wreg<<<16*96, 512, 0, stream>>>(Whh0, WihL, WhhL, wsd);

    dim3 grid(NGROUPS * 16), block(NTHM);
    void* args[] = {(void*)&x, (void*)&wsd, (void*)&out,
                    (void*)&Whh0, (void*)&WihL, (void*)&WhhL};
    if (wspack) {
        hipError_t err = hipLaunchCooperativeKernel((const void*)lstm_pipe<true>,
                                                    grid, block, args, 0, stream);
        if (err != hipSuccess)
            lstm_pipe<true><<<grid, block, 0, stream>>>(x, wsd, out, Whh0, WihL, WhhL);
    } else {
        hipError_t err = hipLaunchCooperativeKernel((const void*)lstm_pipe<false>,
                                                    grid, block, args, 0, stream);
        if (err != hipSuccess)
            lstm_pipe<false><<<grid, block, 0, stream>>>(x, wsd, out, Whh0, WihL, WhhL);
    }
}